// Round 10
// baseline (149.723 us; speedup 1.0000x reference)
//
#include <hip/hip_runtime.h>
#include <hip/hip_bf16.h>
#include <math.h>

#define BATCH 4096
#define INDIM 512
#define NDIM  1024
#define NG    16

typedef __bf16 bf16_t;
typedef __bf16 bf16x8 __attribute__((ext_vector_type(8)));
typedef float  f32x4  __attribute__((ext_vector_type(4)));
typedef unsigned int u32;
typedef unsigned int u32x4 __attribute__((ext_vector_type(4)));

__device__ __forceinline__ float gelu_exact(float v) {
    return 0.5f * v * (1.0f + erff(v * 0.70710678118654752440f));
}

__device__ __forceinline__ void gload_lds16(const void* g, void* l) {
    __builtin_amdgcn_global_load_lds((const __attribute__((address_space(1))) void*)g,
                                     (__attribute__((address_space(3))) void*)l,
                                     16, 0, 0);
}

__device__ __forceinline__ u32 pkbf(float a, float b) {
    union { bf16_t h[2]; u32 v; } x;
    x.h[0] = (bf16_t)a; x.h[1] = (bf16_t)b;
    return x.v;
}

// ---------------- deterministic per-genre bucketing ----------------
__global__ __launch_bounds__(256)
void build_perm_kernel(const int* __restrict__ genre,
                       int* __restrict__ perm,
                       int* __restrict__ offsets /* NG+1 ints */) {
    __shared__ int cc[64][NG];
    __shared__ int gtot[NG];
    __shared__ int goff[NG];
    const int t = threadIdx.x;
    for (int i = t; i < 64 * NG; i += 256) (&cc[0][0])[i] = 0;
    __syncthreads();
    if (t < 64) {
        #pragma unroll 1
        for (int i = 0; i < 64; ++i) {
            int g = genre[t * 64 + i] & (NG - 1);
            cc[t][g] += 1;
        }
    }
    __syncthreads();
    if (t < NG) {
        int s = 0;
        #pragma unroll 1
        for (int c = 0; c < 64; ++c) { int v = cc[c][t]; cc[c][t] = s; s += v; }
        gtot[t] = s;
    }
    __syncthreads();
    if (t == 0) {
        int s = 0;
        for (int g = 0; g < NG; ++g) { goff[g] = s; offsets[g] = s; s += gtot[g]; }
        offsets[NG] = s;
    }
    __syncthreads();
    if (t < 64) {
        #pragma unroll 1
        for (int i = 0; i < 64; ++i) {
            int b = t * 64 + i;
            int g = genre[b] & (NG - 1);
            int pos = goff[g] + cc[t][g];
            cc[t][g] += 1;
            perm[pos] = b;
        }
    }
}

// ---------------- x: fp32 -> bf16 ----------------
__global__ __launch_bounds__(256)
void convert_x_kernel(const float* __restrict__ src, bf16_t* __restrict__ dst) {
    const int i = (blockIdx.x * 256 + threadIdx.x) * 8;  // grid sized exactly
    float4 a = *(const float4*)&src[i];
    float4 b = *(const float4*)&src[i + 4];
    bf16x8 w;
    w[0] = (bf16_t)a.x; w[1] = (bf16_t)a.y; w[2] = (bf16_t)a.z; w[3] = (bf16_t)a.w;
    w[4] = (bf16_t)b.x; w[5] = (bf16_t)b.y; w[6] = (bf16_t)b.z; w[7] = (bf16_t)b.w;
    *(bf16x8*)&dst[i] = w;
}

// ------- weight transpose+convert v3 (strip + pipeline) -------
// fp32 [K][N] -> bf16 [N][K]. One block owns a 64-col n-band of one slab and
// loops over all K/64 k-tiles with a 1-deep software pipeline: loads of tile
// t+1 issue before waiting (counted vmcnt) on tile t; LDS double-buffered;
// one barrier per tile. 512 blocks (big case) x 16 pipelined tiles replaces
// r9's 8192 single-shot blocks (whose serial load->LDS->store chains were the
// measured bottleneck).
template<int K>
struct TStrip {
    u32 T[2][64][34];
};

template<int K>
__device__ __forceinline__ void transpose_strip_body(const float* __restrict__ src,
                                                     bf16_t* __restrict__ dst,
                                                     int N, int n0, int t) {
    __shared__ u32 T[2][64][34];   // 17.4 KB, [buf][n][kpair] stride 34
    constexpr int NT = K / 64;

    const int kp_l = t >> 4;          // 0..15
    const int nc   = (t & 15) * 4;    // 0..60
    const int kr0  = kp_l * 2;        // rows kr0, kr0+1, kr0+32, kr0+33
    const int n    = t >> 2;          // 0..63  (flush mapping)
    const int c8   = (t & 3) * 8;     // 0,8,16,24

    f32x4 ra[4], rb[4];

    auto load = [&](f32x4* r, int kt) {
        const float* p = src + (size_t)(kt * 64 + kr0) * N + n0 + nc;
        r[0] = *(const f32x4*)p;
        r[1] = *(const f32x4*)(p + N);
        r[2] = *(const f32x4*)(p + 32 * N);
        r[3] = *(const f32x4*)(p + 33 * N);
        __builtin_amdgcn_sched_barrier(0);   // pin prefetch issue point
    };
    auto pack = [&](const f32x4* r, int buf) {
        T[buf][nc + 0][kp_l]      = pkbf(r[0][0], r[1][0]);
        T[buf][nc + 1][kp_l]      = pkbf(r[0][1], r[1][1]);
        T[buf][nc + 2][kp_l]      = pkbf(r[0][2], r[1][2]);
        T[buf][nc + 3][kp_l]      = pkbf(r[0][3], r[1][3]);
        T[buf][nc + 0][16 + kp_l] = pkbf(r[2][0], r[3][0]);
        T[buf][nc + 1][16 + kp_l] = pkbf(r[2][1], r[3][1]);
        T[buf][nc + 2][16 + kp_l] = pkbf(r[2][2], r[3][2]);
        T[buf][nc + 3][16 + kp_l] = pkbf(r[2][3], r[3][3]);
    };
    auto flush = [&](int buf, int kt) {
        u32 v[8];
        #pragma unroll
        for (int j = 0; j < 8; ++j) v[j] = T[buf][n][c8 + j];
        u32* d = (u32*)((char*)dst + ((size_t)(n0 + n) * K + kt * 64) * 2) + c8;
        *(u32x4*)(d)     = (u32x4){v[0], v[1], v[2], v[3]};
        *(u32x4*)(d + 4) = (u32x4){v[4], v[5], v[6], v[7]};
    };

    // step(t): cur regs hold tile t; issue load of t+1 into next.
    auto step = [&](int kt, f32x4* cur, f32x4* nxt) {
        const int buf = kt & 1;
        if (kt + 1 < NT) load(nxt, kt + 1);
        // vmcnt bookkeeping (program order): [load(kt) x4][stores(kt-1) x2][load(kt+1) x4]
        if (kt == 0) {
            if (NT > 1) asm volatile("s_waitcnt vmcnt(4)" ::: "memory");
            else        asm volatile("s_waitcnt vmcnt(0)" ::: "memory");
        } else if (kt + 1 < NT) {
            asm volatile("s_waitcnt vmcnt(6)" ::: "memory");
        } else {
            asm volatile("s_waitcnt vmcnt(2)" ::: "memory");
        }
        pack(cur, buf);
        asm volatile("s_waitcnt lgkmcnt(0)" ::: "memory");
        asm volatile("s_barrier" ::: "memory");
        flush(buf, kt);
    };

    load(ra, 0);
    #pragma unroll
    for (int kt = 0; kt < NT; kt += 2) {
        step(kt, ra, rb);
        step(kt + 1, rb, ra);
    }
}

template<int K>
__global__ __launch_bounds__(256)
void transpose_strip_kernel(const float* __restrict__ src, bf16_t* __restrict__ dst,
                            int N) {
    const size_t slab = (size_t)blockIdx.z * (size_t)K * (size_t)N;
    transpose_strip_body<K>(src + slab, dst + slab, N, blockIdx.x * 64, threadIdx.x);
}

// Wa and Wb in one launch: z in [0,32), z<16 -> Wa slab z, else Wb slab z-16.
__global__ __launch_bounds__(256)
void transpose_strip2_kernel(const float* __restrict__ srcA, bf16_t* __restrict__ dstA,
                             const float* __restrict__ srcB, bf16_t* __restrict__ dstB) {
    const int z = blockIdx.z;
    const size_t slab = (size_t)(z & 15) * NDIM * NDIM;
    const float* s = (z < 16 ? srcA : srcB) + slab;
    bf16_t*      d = (z < 16 ? dstA : dstB) + slab;
    transpose_strip_body<NDIM>(s, d, NDIM, blockIdx.x * 64, threadIdx.x);
}

// ---- 128x128 MFMA GEMM, 1024 threads (16 waves, 4x4), 2-phase + T2 XOR swizzle ----
// (exact round-6/9 structure: measured champion)
template<bool EXPERT, bool GATHER_A, bool GELU_OUT, bool SCATTER_OUT, bool OUT_BF16>
__global__ __launch_bounds__(1024, 4)
void gemm128_kernel(const bf16_t* __restrict__ A,
                    const bf16_t* __restrict__ Bt,
                    const float* __restrict__ bias,
                    void* __restrict__ Cout,
                    int K,
                    const int* __restrict__ perm,
                    const int* __restrict__ offsets) {
    constexpr int N = NDIM;
    __shared__ bf16_t As[2][128 * 64];  // [row][k], row stride 128B, linear dest
    __shared__ bf16_t Bs[2][128 * 64];  // [n][k]

    const int n0 = blockIdx.y * 128;
    int m0 = 0, mloc0 = 0, count = 1 << 30, gbase = 0;
    const bf16_t* Bp = Bt;
    const float* biasp = bias;

    if constexpr (EXPERT) {
        const int bx = blockIdx.x;
        int g = 0, accum = 0, cnt = 0;
        for (; g < NG; ++g) {
            cnt = offsets[g + 1] - offsets[g];
            int nt = (cnt + 127) >> 7;
            if (bx < accum + nt) break;
            accum += nt;
        }
        if (g >= NG) return;  // beyond real tile total (whole block exits pre-barrier)
        count = cnt;
        mloc0 = (bx - accum) * 128;
        gbase = offsets[g];
        m0 = gbase + mloc0;
        Bp = Bt + (size_t)g * N * NDIM;
        biasp = bias + g * N;
    } else {
        m0 = blockIdx.x * 128;
    }

    const int tid  = threadIdx.x;
    const int wave = tid >> 6;
    const int lane = tid & 63;
    const int l15  = lane & 15;
    const int l16  = lane >> 4;
    const int wr   = wave >> 2;   // 0..3 -> 32-row band
    const int wc   = wave & 3;    // 0..3 -> 32-col band

    // staging: thread t covers LDS row (t>>3), in-row 16B chunk (t&7).
    // Swizzled global source chunk = (t&7) ^ (row&7) = (t&7) ^ ((t>>3)&7).
    const int srow   = tid >> 3;
    const int srcoff = (((tid & 7) ^ ((tid >> 3) & 7)) * 16);
    int arow;
    if constexpr (EXPERT) {
        int rcl = mloc0 + srow;
        if (rcl >= count) rcl = count - 1;   // clamp tail inside genre
        arow = GATHER_A ? perm[gbase + rcl] : (gbase + rcl);
    } else {
        arow = m0 + srow;
    }
    const char* aptr = (const char*)(A + (size_t)arow * K) + srcoff;
    const char* bptr = (const char*)(Bp + (size_t)(n0 + srow) * K) + srcoff;

    f32x4 acc[2][2];
    #pragma unroll
    for (int m = 0; m < 2; ++m)
        #pragma unroll
        for (int n = 0; n < 2; ++n)
            acc[m][n] = (f32x4){0.f, 0.f, 0.f, 0.f};

    const int nsteps = K >> 6;
    const int w1024 = wave * 1024;

    // 2 x global_load_lds(16B) per thread per stage (1 A + 1 B)
    auto stage = [&](int buf, int t) {
        const size_t ko = (size_t)t * 128;  // 64 bf16 = 128 bytes along K
        gload_lds16(aptr + ko, (char*)&As[buf][0] + w1024);
        gload_lds16(bptr + ko, (char*)&Bs[buf][0] + w1024);
    };

    stage(0, 0);
    int cur = 0;
    for (int t = 0; t < nsteps; ++t) {
        if (t + 1 < nsteps) {
            stage(cur ^ 1, t + 1);
            // wait only for STAGE(t)'s 2 loads; STAGE(t+1)'s 2 stay in flight
            asm volatile("s_waitcnt vmcnt(2)" ::: "memory");
        } else {
            asm volatile("s_waitcnt vmcnt(0)" ::: "memory");
        }
        asm volatile("s_barrier" ::: "memory");

        #pragma unroll
        for (int kk = 0; kk < 2; ++kk) {
            bf16x8 a[2], b[2];
            #pragma unroll
            for (int m = 0; m < 2; ++m) {
                const int row = wr * 32 + m * 16 + l15;
                const int chunk = (kk * 4 + l16) ^ (lane & 7);  // swizzled read
                a[m] = *(const bf16x8*)&As[cur][row * 64 + chunk * 8];
            }
            #pragma unroll
            for (int n = 0; n < 2; ++n) {
                const int row = wc * 32 + n * 16 + l15;
                const int chunk = (kk * 4 + l16) ^ (lane & 7);
                b[n] = *(const bf16x8*)&Bs[cur][row * 64 + chunk * 8];
            }
            #pragma unroll
            for (int m = 0; m < 2; ++m)
                #pragma unroll
                for (int n = 0; n < 2; ++n)
                    acc[m][n] = __builtin_amdgcn_mfma_f32_16x16x32_bf16(a[m], b[n], acc[m][n], 0, 0, 0);
        }
        asm volatile("s_barrier" ::: "memory");  // reads done before buf[cur] is re-staged
        cur ^= 1;
    }

    // ---- epilogue: bias (+GELU), masked/scattered store
    #pragma unroll
    for (int n = 0; n < 2; ++n) {
        const int col = n0 + wc * 32 + n * 16 + l15;
        const float bv = biasp[col];
        #pragma unroll
        for (int m = 0; m < 2; ++m) {
            #pragma unroll
            for (int r = 0; r < 4; ++r) {
                const int row_local = wr * 32 + m * 16 + l16 * 4 + r;
                if constexpr (EXPERT) {
                    if (mloc0 + row_local >= count) continue;
                }
                float v = acc[m][n][r] + bv;
                if constexpr (GELU_OUT) v = gelu_exact(v);
                int orow = m0 + row_local;
                if constexpr (SCATTER_OUT) orow = perm[orow];
                if constexpr (OUT_BF16)
                    ((bf16_t*)Cout)[(size_t)orow * N + col] = (bf16_t)v;
                else
                    ((float*)Cout)[(size_t)orow * N + col] = v;
            }
        }
    }
}

extern "C" void kernel_launch(void* const* d_in, const int* in_sizes, int n_in,
                              void* d_out, int out_size, void* d_ws, size_t ws_size,
                              hipStream_t stream) {
    const float* x     = (const float*)d_in[0];
    const int*   genre = (const int*)  d_in[1];
    const float* W1    = (const float*)d_in[2];
    const float* b1    = (const float*)d_in[3];
    const float* W2    = (const float*)d_in[4];
    const float* b2    = (const float*)d_in[5];
    const float* Wa    = (const float*)d_in[6];
    const float* ba    = (const float*)d_in[7];
    const float* Wb    = (const float*)d_in[8];
    const float* bb    = (const float*)d_in[9];
    float* out = (float*)d_out;

    char* ws = (char*)d_ws;
    const size_t MB = 1 << 20;
    bf16_t* W1t = (bf16_t*)(ws);                 // 1 MB  [1024][512]
    bf16_t* W2t = (bf16_t*)(ws + 1 * MB);        // 2 MB  [1024][1024]
    bf16_t* Wat = (bf16_t*)(ws + 3 * MB);        // 32 MB [16][1024][1024]
    bf16_t* Wbt = (bf16_t*)(ws + 35 * MB);       // 32 MB
    bf16_t* xb  = (bf16_t*)(ws + 67 * MB);       // 4 MB  [4096][512]
    bf16_t* s1b = (bf16_t*)(ws + 71 * MB);       // 8 MB  [4096][1024] (reused as h)
    bf16_t* sb  = (bf16_t*)(ws + 79 * MB);       // 8 MB
    int*    perm    = (int*)(ws + 87 * MB);      // 16 KB
    int*    offsets = (int*)(ws + 87 * MB + 65536);
    bf16_t* hb = s1b;  // s1 dead after GEMM2

    build_perm_kernel<<<1, 256, 0, stream>>>(genre, perm, offsets);
    convert_x_kernel<<<BATCH * INDIM / (256 * 8), 256, 0, stream>>>(x, xb);
    // W1: [512][1024] -> [1024][512]; W2: [1024][1024] -> [1024][1024]
    transpose_strip_kernel<INDIM><<<dim3(NDIM / 64, 1, 1), 256, 0, stream>>>(W1, W1t, NDIM);
    transpose_strip_kernel<NDIM><<<dim3(NDIM / 64, 1, 1), 256, 0, stream>>>(W2, W2t, NDIM);
    transpose_strip2_kernel<<<dim3(NDIM / 64, 1, 2 * NG), 256, 0, stream>>>(
        Wa, Wat, Wb, Wbt);

    // trunk: s1 = gelu(x @ W1 + b1)
    gemm128_kernel<false, false, true, false, true><<<dim3(32, 8), 1024, 0, stream>>>(
        xb, W1t, b1, s1b, INDIM, nullptr, nullptr);
    // trunk: s = gelu(s1 @ W2 + b2)
    gemm128_kernel<false, false, true, false, true><<<dim3(32, 8), 1024, 0, stream>>>(
        s1b, W2t, b2, sb, NDIM, nullptr, nullptr);
    // experts: h[perm-space] = gelu(s[perm] @ Wa[g] + ba[g])
    gemm128_kernel<true, true, true, false, true><<<dim3(48, 8), 1024, 0, stream>>>(
        sb, Wat, ba, hb, NDIM, perm, offsets);
    // experts: out[perm] = h @ Wb[g] + bb[g]
    gemm128_kernel<true, false, false, true, false><<<dim3(48, 8), 1024, 0, stream>>>(
        hb, Wbt, bb, out, NDIM, perm, offsets);
}

// Round 11
// 148.877 us; speedup vs baseline: 1.0057x; 1.0057x over previous
//
#include <hip/hip_runtime.h>
#include <hip/hip_bf16.h>
#include <math.h>

#define BATCH 4096
#define INDIM 512
#define NDIM  1024
#define NG    16

typedef __bf16 bf16_t;
typedef __bf16 bf16x8 __attribute__((ext_vector_type(8)));
typedef float  f32x4  __attribute__((ext_vector_type(4)));
typedef unsigned int u32;
typedef unsigned int u32x4 __attribute__((ext_vector_type(4)));

__device__ __forceinline__ float gelu_exact(float v) {
    return 0.5f * v * (1.0f + erff(v * 0.70710678118654752440f));
}

__device__ __forceinline__ void gload_lds16(const void* g, void* l) {
    __builtin_amdgcn_global_load_lds((const __attribute__((address_space(1))) void*)g,
                                     (__attribute__((address_space(3))) void*)l,
                                     16, 0, 0);
}

__device__ __forceinline__ u32 pkbf(float a, float b) {
    union { bf16_t h[2]; u32 v; } x;
    x.h[0] = (bf16_t)a; x.h[1] = (bf16_t)b;
    return x.v;
}

// ---------------- deterministic per-genre bucketing ----------------
__global__ __launch_bounds__(256)
void build_perm_kernel(const int* __restrict__ genre,
                       int* __restrict__ perm,
                       int* __restrict__ offsets /* NG+1 ints */) {
    __shared__ int cc[64][NG];
    __shared__ int gtot[NG];
    __shared__ int goff[NG];
    const int t = threadIdx.x;
    for (int i = t; i < 64 * NG; i += 256) (&cc[0][0])[i] = 0;
    __syncthreads();
    if (t < 64) {
        #pragma unroll 1
        for (int i = 0; i < 64; ++i) {
            int g = genre[t * 64 + i] & (NG - 1);
            cc[t][g] += 1;
        }
    }
    __syncthreads();
    if (t < NG) {
        int s = 0;
        #pragma unroll 1
        for (int c = 0; c < 64; ++c) { int v = cc[c][t]; cc[c][t] = s; s += v; }
        gtot[t] = s;
    }
    __syncthreads();
    if (t == 0) {
        int s = 0;
        for (int g = 0; g < NG; ++g) { goff[g] = s; offsets[g] = s; s += gtot[g]; }
        offsets[NG] = s;
    }
    __syncthreads();
    if (t < 64) {
        #pragma unroll 1
        for (int i = 0; i < 64; ++i) {
            int b = t * 64 + i;
            int g = genre[b] & (NG - 1);
            int pos = goff[g] + cc[t][g];
            cc[t][g] += 1;
            perm[pos] = b;
        }
    }
}

// ---------------- x: fp32 -> bf16 ----------------
__global__ __launch_bounds__(256)
void convert_x_kernel(const float* __restrict__ src, bf16_t* __restrict__ dst) {
    const int i = (blockIdx.x * 256 + threadIdx.x) * 8;  // grid sized exactly
    float4 a = *(const float4*)&src[i];
    float4 b = *(const float4*)&src[i + 4];
    bf16x8 w;
    w[0] = (bf16_t)a.x; w[1] = (bf16_t)a.y; w[2] = (bf16_t)a.z; w[3] = (bf16_t)a.w;
    w[4] = (bf16_t)b.x; w[5] = (bf16_t)b.y; w[6] = (bf16_t)b.z; w[7] = (bf16_t)b.w;
    *(bf16x8*)&dst[i] = w;
}

// ------- weight transpose+convert v4: strip + 2-DEEP pipeline + K-split -------
// fp32 [K][N] -> bf16 [N][K]. One block owns a 64-col n-band x K/2 k-range and
// loops NT k-tiles. r10 post-mortem: 1-deep prefetch exposed ~500cy of the
// ~900cy HBM latency per tile (2 blocks/CU, nothing to hide it). Fix: loads
// issue 2 tiles ahead (f32x4 r[3][4], statically indexed via full unroll) and
// 2x K-split doubles blocks/CU. Counted vmcnt by issue-order bookkeeping:
// steady state waits vmcnt(10) = [S(kt-2)2 done][L(kt)4 done | L(kt+1)4,
// S(kt-1)2, L(kt+2)4 in flight].
template<int NT>
__device__ __forceinline__ void transpose_strip_body(const float* __restrict__ src,
                                                     bf16_t* __restrict__ dst,
                                                     int N, int K, int n0, int kbase,
                                                     int t) {
    __shared__ u32 T[2][64][34];   // 17.4 KB, [buf][n][kpair] stride 34

    const int kp_l = t >> 4;          // 0..15
    const int nc   = (t & 15) * 4;    // 0..60
    const int kr0  = kp_l * 2;        // rows kr0, kr0+1, kr0+32, kr0+33
    const int n    = t >> 2;          // 0..63  (flush mapping)
    const int c8   = (t & 3) * 8;     // 0,8,16,24

    f32x4 r[3][4];                    // 3-slot reg ring (static after full unroll)

    auto load = [&](int slot, int kt) {
        const float* p = src + (size_t)(kbase + kt * 64 + kr0) * N + n0 + nc;
        r[slot][0] = *(const f32x4*)p;
        r[slot][1] = *(const f32x4*)(p + N);
        r[slot][2] = *(const f32x4*)(p + 32 * N);
        r[slot][3] = *(const f32x4*)(p + 33 * N);
        __builtin_amdgcn_sched_barrier(0);   // pin issue point
    };
    auto pack = [&](int slot, int buf) {
        T[buf][nc + 0][kp_l]      = pkbf(r[slot][0][0], r[slot][1][0]);
        T[buf][nc + 1][kp_l]      = pkbf(r[slot][0][1], r[slot][1][1]);
        T[buf][nc + 2][kp_l]      = pkbf(r[slot][0][2], r[slot][1][2]);
        T[buf][nc + 3][kp_l]      = pkbf(r[slot][0][3], r[slot][1][3]);
        T[buf][nc + 0][16 + kp_l] = pkbf(r[slot][2][0], r[slot][3][0]);
        T[buf][nc + 1][16 + kp_l] = pkbf(r[slot][2][1], r[slot][3][1]);
        T[buf][nc + 2][16 + kp_l] = pkbf(r[slot][2][2], r[slot][3][2]);
        T[buf][nc + 3][16 + kp_l] = pkbf(r[slot][2][3], r[slot][3][3]);
    };
    auto flush = [&](int buf, int kt) {
        u32 v[8];
        #pragma unroll
        for (int j = 0; j < 8; ++j) v[j] = T[buf][n][c8 + j];
        u32* d = (u32*)((char*)dst + ((size_t)(n0 + n) * K + kbase + kt * 64) * 2) + c8;
        *(u32x4*)(d)     = (u32x4){v[0], v[1], v[2], v[3]};
        *(u32x4*)(d + 4) = (u32x4){v[4], v[5], v[6], v[7]};
    };

    load(0, 0);
    load(1, 1);
    #pragma unroll
    for (int kt = 0; kt < NT; ++kt) {
        if (kt + 2 < NT) load((kt + 2) % 3, kt + 2);
        // issue-order vmcnt: ops newer than L(kt) at this point
        if (kt == 0)           asm volatile("s_waitcnt vmcnt(8)"  ::: "memory");
        else if (kt + 2 < NT)  asm volatile("s_waitcnt vmcnt(10)" ::: "memory");
        else if (kt + 1 < NT)  asm volatile("s_waitcnt vmcnt(6)"  ::: "memory");
        else                   asm volatile("s_waitcnt vmcnt(2)"  ::: "memory");
        pack(kt % 3, kt & 1);
        asm volatile("s_waitcnt lgkmcnt(0)" ::: "memory");
        asm volatile("s_barrier" ::: "memory");
        flush(kt & 1, kt);
    }
}

template<int NT>
__global__ __launch_bounds__(256)
void transpose_strip_kernel(const float* __restrict__ src, bf16_t* __restrict__ dst,
                            int N, int K) {
    const size_t slab = (size_t)blockIdx.z * (size_t)K * (size_t)N;
    transpose_strip_body<NT>(src + slab, dst + slab, N, K, blockIdx.x * 64,
                             blockIdx.y * (NT * 64), threadIdx.x);
}

// Wa and Wb in one launch: z in [0,32), z<16 -> Wa slab z, else Wb slab z-16.
__global__ __launch_bounds__(256)
void transpose_strip2_kernel(const float* __restrict__ srcA, bf16_t* __restrict__ dstA,
                             const float* __restrict__ srcB, bf16_t* __restrict__ dstB) {
    const int z = blockIdx.z;
    const size_t slab = (size_t)(z & 15) * NDIM * NDIM;
    const float* s = (z < 16 ? srcA : srcB) + slab;
    bf16_t*      d = (z < 16 ? dstA : dstB) + slab;
    transpose_strip_body<NDIM / 128>(s, d, NDIM, NDIM, blockIdx.x * 64,
                                     blockIdx.y * (NDIM / 2), threadIdx.x);
}

// ---- 128x128 MFMA GEMM, 1024 threads (16 waves, 4x4), 2-phase + T2 XOR swizzle ----
// (exact round-6/9 structure: measured champion)
template<bool EXPERT, bool GATHER_A, bool GELU_OUT, bool SCATTER_OUT, bool OUT_BF16>
__global__ __launch_bounds__(1024, 4)
void gemm128_kernel(const bf16_t* __restrict__ A,
                    const bf16_t* __restrict__ Bt,
                    const float* __restrict__ bias,
                    void* __restrict__ Cout,
                    int K,
                    const int* __restrict__ perm,
                    const int* __restrict__ offsets) {
    constexpr int N = NDIM;
    __shared__ bf16_t As[2][128 * 64];  // [row][k], row stride 128B, linear dest
    __shared__ bf16_t Bs[2][128 * 64];  // [n][k]

    const int n0 = blockIdx.y * 128;
    int m0 = 0, mloc0 = 0, count = 1 << 30, gbase = 0;
    const bf16_t* Bp = Bt;
    const float* biasp = bias;

    if constexpr (EXPERT) {
        const int bx = blockIdx.x;
        int g = 0, accum = 0, cnt = 0;
        for (; g < NG; ++g) {
            cnt = offsets[g + 1] - offsets[g];
            int nt = (cnt + 127) >> 7;
            if (bx < accum + nt) break;
            accum += nt;
        }
        if (g >= NG) return;  // beyond real tile total (whole block exits pre-barrier)
        count = cnt;
        mloc0 = (bx - accum) * 128;
        gbase = offsets[g];
        m0 = gbase + mloc0;
        Bp = Bt + (size_t)g * N * NDIM;
        biasp = bias + g * N;
    } else {
        m0 = blockIdx.x * 128;
    }

    const int tid  = threadIdx.x;
    const int wave = tid >> 6;
    const int lane = tid & 63;
    const int l15  = lane & 15;
    const int l16  = lane >> 4;
    const int wr   = wave >> 2;   // 0..3 -> 32-row band
    const int wc   = wave & 3;    // 0..3 -> 32-col band

    // staging: thread t covers LDS row (t>>3), in-row 16B chunk (t&7).
    // Swizzled global source chunk = (t&7) ^ (row&7) = (t&7) ^ ((t>>3)&7).
    const int srow   = tid >> 3;
    const int srcoff = (((tid & 7) ^ ((tid >> 3) & 7)) * 16);
    int arow;
    if constexpr (EXPERT) {
        int rcl = mloc0 + srow;
        if (rcl >= count) rcl = count - 1;   // clamp tail inside genre
        arow = GATHER_A ? perm[gbase + rcl] : (gbase + rcl);
    } else {
        arow = m0 + srow;
    }
    const char* aptr = (const char*)(A + (size_t)arow * K) + srcoff;
    const char* bptr = (const char*)(Bp + (size_t)(n0 + srow) * K) + srcoff;

    f32x4 acc[2][2];
    #pragma unroll
    for (int m = 0; m < 2; ++m)
        #pragma unroll
        for (int n = 0; n < 2; ++n)
            acc[m][n] = (f32x4){0.f, 0.f, 0.f, 0.f};

    const int nsteps = K >> 6;
    const int w1024 = wave * 1024;

    // 2 x global_load_lds(16B) per thread per stage (1 A + 1 B)
    auto stage = [&](int buf, int t) {
        const size_t ko = (size_t)t * 128;  // 64 bf16 = 128 bytes along K
        gload_lds16(aptr + ko, (char*)&As[buf][0] + w1024);
        gload_lds16(bptr + ko, (char*)&Bs[buf][0] + w1024);
    };

    stage(0, 0);
    int cur = 0;
    for (int t = 0; t < nsteps; ++t) {
        if (t + 1 < nsteps) {
            stage(cur ^ 1, t + 1);
            // wait only for STAGE(t)'s 2 loads; STAGE(t+1)'s 2 stay in flight
            asm volatile("s_waitcnt vmcnt(2)" ::: "memory");
        } else {
            asm volatile("s_waitcnt vmcnt(0)" ::: "memory");
        }
        asm volatile("s_barrier" ::: "memory");

        #pragma unroll
        for (int kk = 0; kk < 2; ++kk) {
            bf16x8 a[2], b[2];
            #pragma unroll
            for (int m = 0; m < 2; ++m) {
                const int row = wr * 32 + m * 16 + l15;
                const int chunk = (kk * 4 + l16) ^ (lane & 7);  // swizzled read
                a[m] = *(const bf16x8*)&As[cur][row * 64 + chunk * 8];
            }
            #pragma unroll
            for (int n = 0; n < 2; ++n) {
                const int row = wc * 32 + n * 16 + l15;
                const int chunk = (kk * 4 + l16) ^ (lane & 7);
                b[n] = *(const bf16x8*)&Bs[cur][row * 64 + chunk * 8];
            }
            #pragma unroll
            for (int m = 0; m < 2; ++m)
                #pragma unroll
                for (int n = 0; n < 2; ++n)
                    acc[m][n] = __builtin_amdgcn_mfma_f32_16x16x32_bf16(a[m], b[n], acc[m][n], 0, 0, 0);
        }
        asm volatile("s_barrier" ::: "memory");  // reads done before buf[cur] is re-staged
        cur ^= 1;
    }

    // ---- epilogue: bias (+GELU), masked/scattered store
    #pragma unroll
    for (int n = 0; n < 2; ++n) {
        const int col = n0 + wc * 32 + n * 16 + l15;
        const float bv = biasp[col];
        #pragma unroll
        for (int m = 0; m < 2; ++m) {
            #pragma unroll
            for (int r = 0; r < 4; ++r) {
                const int row_local = wr * 32 + m * 16 + l16 * 4 + r;
                if constexpr (EXPERT) {
                    if (mloc0 + row_local >= count) continue;
                }
                float v = acc[m][n][r] + bv;
                if constexpr (GELU_OUT) v = gelu_exact(v);
                int orow = m0 + row_local;
                if constexpr (SCATTER_OUT) orow = perm[orow];
                if constexpr (OUT_BF16)
                    ((bf16_t*)Cout)[(size_t)orow * N + col] = (bf16_t)v;
                else
                    ((float*)Cout)[(size_t)orow * N + col] = v;
            }
        }
    }
}

extern "C" void kernel_launch(void* const* d_in, const int* in_sizes, int n_in,
                              void* d_out, int out_size, void* d_ws, size_t ws_size,
                              hipStream_t stream) {
    const float* x     = (const float*)d_in[0];
    const int*   genre = (const int*)  d_in[1];
    const float* W1    = (const float*)d_in[2];
    const float* b1    = (const float*)d_in[3];
    const float* W2    = (const float*)d_in[4];
    const float* b2    = (const float*)d_in[5];
    const float* Wa    = (const float*)d_in[6];
    const float* ba    = (const float*)d_in[7];
    const float* Wb    = (const float*)d_in[8];
    const float* bb    = (const float*)d_in[9];
    float* out = (float*)d_out;

    char* ws = (char*)d_ws;
    const size_t MB = 1 << 20;
    bf16_t* W1t = (bf16_t*)(ws);                 // 1 MB  [1024][512]
    bf16_t* W2t = (bf16_t*)(ws + 1 * MB);        // 2 MB  [1024][1024]
    bf16_t* Wat = (bf16_t*)(ws + 3 * MB);        // 32 MB [16][1024][1024]
    bf16_t* Wbt = (bf16_t*)(ws + 35 * MB);       // 32 MB
    bf16_t* xb  = (bf16_t*)(ws + 67 * MB);       // 4 MB  [4096][512]
    bf16_t* s1b = (bf16_t*)(ws + 71 * MB);       // 8 MB  [4096][1024] (reused as h)
    bf16_t* sb  = (bf16_t*)(ws + 79 * MB);       // 8 MB
    int*    perm    = (int*)(ws + 87 * MB);      // 16 KB
    int*    offsets = (int*)(ws + 87 * MB + 65536);
    bf16_t* hb = s1b;  // s1 dead after GEMM2

    build_perm_kernel<<<1, 256, 0, stream>>>(genre, perm, offsets);
    convert_x_kernel<<<BATCH * INDIM / (256 * 8), 256, 0, stream>>>(x, xb);
    // W1: [512][1024] -> [1024][512] (NT=4 per half); W2: [1024][1024] (NT=8)
    transpose_strip_kernel<INDIM / 128><<<dim3(NDIM / 64, 2, 1), 256, 0, stream>>>(
        W1, W1t, NDIM, INDIM);
    transpose_strip_kernel<NDIM / 128><<<dim3(NDIM / 64, 2, 1), 256, 0, stream>>>(
        W2, W2t, NDIM, NDIM);
    transpose_strip2_kernel<<<dim3(NDIM / 64, 2, 2 * NG), 256, 0, stream>>>(
        Wa, Wat, Wb, Wbt);

    // trunk: s1 = gelu(x @ W1 + b1)
    gemm128_kernel<false, false, true, false, true><<<dim3(32, 8), 1024, 0, stream>>>(
        xb, W1t, b1, s1b, INDIM, nullptr, nullptr);
    // trunk: s = gelu(s1 @ W2 + b2)
    gemm128_kernel<false, false, true, false, true><<<dim3(32, 8), 1024, 0, stream>>>(
        s1b, W2t, b2, sb, NDIM, nullptr, nullptr);
    // experts: h[perm-space] = gelu(s[perm] @ Wa[g] + ba[g])
    gemm128_kernel<true, true, true, false, true><<<dim3(48, 8), 1024, 0, stream>>>(
        sb, Wat, ba, hb, NDIM, perm, offsets);
    // experts: out[perm] = h @ Wb[g] + bb[g]
    gemm128_kernel<true, false, false, true, false><<<dim3(48, 8), 1024, 0, stream>>>(
        hb, Wbt, bb, out, NDIM, perm, offsets);
}

// Round 12
// 146.690 us; speedup vs baseline: 1.0207x; 1.0149x over previous
//
#include <hip/hip_runtime.h>
#include <hip/hip_bf16.h>
#include <math.h>

#define BATCH 4096
#define INDIM 512
#define NDIM  1024
#define NG    16

typedef __bf16 bf16_t;
typedef __bf16 bf16x8 __attribute__((ext_vector_type(8)));
typedef float  f32x4  __attribute__((ext_vector_type(4)));
typedef unsigned int u32;
typedef unsigned int u32x4 __attribute__((ext_vector_type(4)));

__device__ __forceinline__ float gelu_exact(float v) {
    return 0.5f * v * (1.0f + erff(v * 0.70710678118654752440f));
}

__device__ __forceinline__ void gload_lds16(const void* g, void* l) {
    __builtin_amdgcn_global_load_lds((const __attribute__((address_space(1))) void*)g,
                                     (__attribute__((address_space(3))) void*)l,
                                     16, 0, 0);
}

__device__ __forceinline__ u32 pkbf(float a, float b) {
    union { bf16_t h[2]; u32 v; } x;
    x.h[0] = (bf16_t)a; x.h[1] = (bf16_t)b;
    return x.v;
}

template<int N> __device__ __forceinline__ void waitvm() {
    if constexpr (N == 0)       asm volatile("s_waitcnt vmcnt(0)"  ::: "memory");
    else if constexpr (N == 2)  asm volatile("s_waitcnt vmcnt(2)"  ::: "memory");
    else if constexpr (N == 4)  asm volatile("s_waitcnt vmcnt(4)"  ::: "memory");
    else if constexpr (N == 6)  asm volatile("s_waitcnt vmcnt(6)"  ::: "memory");
    else if constexpr (N == 8)  asm volatile("s_waitcnt vmcnt(8)"  ::: "memory");
    else if constexpr (N == 10) asm volatile("s_waitcnt vmcnt(10)" ::: "memory");
    else                        asm volatile("s_waitcnt vmcnt(12)" ::: "memory");
}

// ---------------- deterministic per-genre bucketing ----------------
__global__ __launch_bounds__(256)
void build_perm_kernel(const int* __restrict__ genre,
                       int* __restrict__ perm,
                       int* __restrict__ offsets /* NG+1 ints */) {
    __shared__ int cc[64][NG];
    __shared__ int gtot[NG];
    __shared__ int goff[NG];
    const int t = threadIdx.x;
    for (int i = t; i < 64 * NG; i += 256) (&cc[0][0])[i] = 0;
    __syncthreads();
    if (t < 64) {
        #pragma unroll 1
        for (int i = 0; i < 64; ++i) {
            int g = genre[t * 64 + i] & (NG - 1);
            cc[t][g] += 1;
        }
    }
    __syncthreads();
    if (t < NG) {
        int s = 0;
        #pragma unroll 1
        for (int c = 0; c < 64; ++c) { int v = cc[c][t]; cc[c][t] = s; s += v; }
        gtot[t] = s;
    }
    __syncthreads();
    if (t == 0) {
        int s = 0;
        for (int g = 0; g < NG; ++g) { goff[g] = s; offsets[g] = s; s += gtot[g]; }
        offsets[NG] = s;
    }
    __syncthreads();
    if (t < 64) {
        #pragma unroll 1
        for (int i = 0; i < 64; ++i) {
            int b = t * 64 + i;
            int g = genre[b] & (NG - 1);
            int pos = goff[g] + cc[t][g];
            cc[t][g] += 1;
            perm[pos] = b;
        }
    }
}

// ---------------- x: fp32 -> bf16 ----------------
__global__ __launch_bounds__(256)
void convert_x_kernel(const float* __restrict__ src, bf16_t* __restrict__ dst) {
    const int i = (blockIdx.x * 256 + threadIdx.x) * 8;  // grid sized exactly
    float4 a = *(const float4*)&src[i];
    float4 b = *(const float4*)&src[i + 4];
    bf16x8 w;
    w[0] = (bf16_t)a.x; w[1] = (bf16_t)a.y; w[2] = (bf16_t)a.z; w[3] = (bf16_t)a.w;
    w[4] = (bf16_t)b.x; w[5] = (bf16_t)b.y; w[6] = (bf16_t)b.z; w[7] = (bf16_t)b.w;
    *(bf16x8*)&dst[i] = w;
}

// ------- weight transpose+convert v5: strip + 2-deep pipeline + 4x K-split +
//         DENSE-per-instruction stores -------
// fp32 [K][N] -> bf16 [N][K]. r11 post-mortem: depth-2 @4 blocks/CU was null.
// This round tests the two remaining hypotheses together: (1) full occupancy
// (8 blocks/CU via 4x K-split), (2) store instructions that write contiguous
// 64B per n-row quad (r9/r11 wrote 16B pieces at 32B stride -> partial-line
// writes). Exact compile-time vmcnt bookkeeping per (kt, NT).
template<int NT>
__device__ __forceinline__ void transpose_strip_body(const float* __restrict__ src,
                                                     bf16_t* __restrict__ dst,
                                                     int N, int K, int n0, int kbase,
                                                     int t) {
    __shared__ u32 T[2][64][34];   // 17.4 KB, [buf][n][kpair] stride 34

    const int kp_l = t >> 4;          // 0..15
    const int nc   = (t & 15) * 4;    // 0..60
    const int kr0  = kp_l * 2;        // rows kr0, kr0+1, kr0+32, kr0+33
    const int n    = t >> 2;          // 0..63  (flush mapping)
    const int c4   = (t & 3) * 4;     // u32 offset in row: 0,4,8,12

    f32x4 r[3][4];                    // 3-slot reg ring (static after full unroll)

    auto load = [&](int slot, int kt) {
        const float* p = src + (size_t)(kbase + kt * 64 + kr0) * N + n0 + nc;
        r[slot][0] = *(const f32x4*)p;
        r[slot][1] = *(const f32x4*)(p + N);
        r[slot][2] = *(const f32x4*)(p + 32 * N);
        r[slot][3] = *(const f32x4*)(p + 33 * N);
        __builtin_amdgcn_sched_barrier(0);   // pin issue point
    };
    auto pack = [&](int slot, int buf) {
        T[buf][nc + 0][kp_l]      = pkbf(r[slot][0][0], r[slot][1][0]);
        T[buf][nc + 1][kp_l]      = pkbf(r[slot][0][1], r[slot][1][1]);
        T[buf][nc + 2][kp_l]      = pkbf(r[slot][0][2], r[slot][1][2]);
        T[buf][nc + 3][kp_l]      = pkbf(r[slot][0][3], r[slot][1][3]);
        T[buf][nc + 0][16 + kp_l] = pkbf(r[slot][2][0], r[slot][3][0]);
        T[buf][nc + 1][16 + kp_l] = pkbf(r[slot][2][1], r[slot][3][1]);
        T[buf][nc + 2][16 + kp_l] = pkbf(r[slot][2][2], r[slot][3][2]);
        T[buf][nc + 3][16 + kp_l] = pkbf(r[slot][2][3], r[slot][3][3]);
    };
    auto flush = [&](int buf, int kt) {
        u32 v[8];
        #pragma unroll
        for (int j = 0; j < 4; ++j) v[j]     = T[buf][n][c4 + j];
        #pragma unroll
        for (int j = 0; j < 4; ++j) v[4 + j] = T[buf][n][16 + c4 + j];
        u32* d = (u32*)((char*)dst + ((size_t)(n0 + n) * K + kbase + kt * 64) * 2);
        // each instruction: 4 lanes x 16B contiguous = dense 64B per n-row
        *(u32x4*)(d + c4)      = (u32x4){v[0], v[1], v[2], v[3]};
        *(u32x4*)(d + 16 + c4) = (u32x4){v[4], v[5], v[6], v[7]};
    };

    load(0, 0);
    if constexpr (NT > 1) load(1, 1);
    #pragma unroll
    for (int kt = 0; kt < NT; ++kt) {
        if (kt + 2 < NT) load((kt + 2) % 3, kt + 2);
        // ops issued after L(kt): S(kt-2)2 + L(kt+1)4 + S(kt-1)2 + L(kt+2)4
        {
            constexpr int B0 = 0;  // (computed per-iteration below; unrolled)
            (void)B0;
        }
        if (kt + 2 < NT) {
            if (kt == 0)      waitvm<8>();       // L(1)4 + L(2)4
            else if (kt == 1) waitvm<10>();      // L(2)4 + S(0)2 + L(3)4
            else              waitvm<10>();      // S2 + L4 + S2 ... (>=kt2: 2+4+2+4=12? no L beyond) -> see below
        } else if (kt + 1 < NT) {
            if (kt == 0)      waitvm<4>();       // L(1)4
            else              waitvm<8>();       // S(kt-2)2 + L(kt+1)4 + S(kt-1)2
        } else {
            if (kt == 0)      waitvm<0>();
            else if (kt == 1) waitvm<2>();       // S(0)2
            else              waitvm<4>();       // S(kt-2)2 + S(kt-1)2
        }
        pack(kt % 3, kt & 1);
        asm volatile("s_waitcnt lgkmcnt(0)" ::: "memory");
        asm volatile("s_barrier" ::: "memory");
        flush(kt & 1, kt);
    }
}

template<int NT>
__global__ __launch_bounds__(256)
void transpose_strip_kernel(const float* __restrict__ src, bf16_t* __restrict__ dst,
                            int N, int K) {
    const size_t slab = (size_t)blockIdx.z * (size_t)K * (size_t)N;
    transpose_strip_body<NT>(src + slab, dst + slab, N, K, blockIdx.x * 64,
                             blockIdx.y * (NT * 64), threadIdx.x);
}

// Wa and Wb in one launch: z in [0,64), z<32 -> Wa slab z>>1, else Wb; y-split via z&1
__global__ __launch_bounds__(256)
void transpose_strip2_kernel(const float* __restrict__ srcA, bf16_t* __restrict__ dstA,
                             const float* __restrict__ srcB, bf16_t* __restrict__ dstB) {
    const int z = blockIdx.z;           // 0..63: slab*2 + khalf... use y for ksplit
    const size_t slab = (size_t)(z & 15) * NDIM * NDIM;
    const float* s = (z < 16 ? srcA : srcB) + slab;
    bf16_t*      d = (z < 16 ? dstA : dstB) + slab;
    transpose_strip_body<NDIM / 256>(s, d, NDIM, NDIM, blockIdx.x * 64,
                                     blockIdx.y * (NDIM / 4), threadIdx.x);
}

// ---- 128x128 MFMA GEMM, 1024 threads (16 waves, 4x4), 2-phase + T2 XOR swizzle ----
// (exact round-6/9/11 structure: measured champion)
template<bool EXPERT, bool GATHER_A, bool GELU_OUT, bool SCATTER_OUT, bool OUT_BF16>
__global__ __launch_bounds__(1024, 4)
void gemm128_kernel(const bf16_t* __restrict__ A,
                    const bf16_t* __restrict__ Bt,
                    const float* __restrict__ bias,
                    void* __restrict__ Cout,
                    int K,
                    const int* __restrict__ perm,
                    const int* __restrict__ offsets) {
    constexpr int N = NDIM;
    __shared__ bf16_t As[2][128 * 64];  // [row][k], row stride 128B, linear dest
    __shared__ bf16_t Bs[2][128 * 64];  // [n][k]

    const int n0 = blockIdx.y * 128;
    int m0 = 0, mloc0 = 0, count = 1 << 30, gbase = 0;
    const bf16_t* Bp = Bt;
    const float* biasp = bias;

    if constexpr (EXPERT) {
        const int bx = blockIdx.x;
        int g = 0, accum = 0, cnt = 0;
        for (; g < NG; ++g) {
            cnt = offsets[g + 1] - offsets[g];
            int nt = (cnt + 127) >> 7;
            if (bx < accum + nt) break;
            accum += nt;
        }
        if (g >= NG) return;  // beyond real tile total (whole block exits pre-barrier)
        count = cnt;
        mloc0 = (bx - accum) * 128;
        gbase = offsets[g];
        m0 = gbase + mloc0;
        Bp = Bt + (size_t)g * N * NDIM;
        biasp = bias + g * N;
    } else {
        m0 = blockIdx.x * 128;
    }

    const int tid  = threadIdx.x;
    const int wave = tid >> 6;
    const int lane = tid & 63;
    const int l15  = lane & 15;
    const int l16  = lane >> 4;
    const int wr   = wave >> 2;   // 0..3 -> 32-row band
    const int wc   = wave & 3;    // 0..3 -> 32-col band

    // staging: thread t covers LDS row (t>>3), in-row 16B chunk (t&7).
    // Swizzled global source chunk = (t&7) ^ (row&7) = (t&7) ^ ((t>>3)&7).
    const int srow   = tid >> 3;
    const int srcoff = (((tid & 7) ^ ((tid >> 3) & 7)) * 16);
    int arow;
    if constexpr (EXPERT) {
        int rcl = mloc0 + srow;
        if (rcl >= count) rcl = count - 1;   // clamp tail inside genre
        arow = GATHER_A ? perm[gbase + rcl] : (gbase + rcl);
    } else {
        arow = m0 + srow;
    }
    const char* aptr = (const char*)(A + (size_t)arow * K) + srcoff;
    const char* bptr = (const char*)(Bp + (size_t)(n0 + srow) * K) + srcoff;

    f32x4 acc[2][2];
    #pragma unroll
    for (int m = 0; m < 2; ++m)
        #pragma unroll
        for (int n = 0; n < 2; ++n)
            acc[m][n] = (f32x4){0.f, 0.f, 0.f, 0.f};

    const int nsteps = K >> 6;
    const int w1024 = wave * 1024;

    // 2 x global_load_lds(16B) per thread per stage (1 A + 1 B)
    auto stage = [&](int buf, int t) {
        const size_t ko = (size_t)t * 128;  // 64 bf16 = 128 bytes along K
        gload_lds16(aptr + ko, (char*)&As[buf][0] + w1024);
        gload_lds16(bptr + ko, (char*)&Bs[buf][0] + w1024);
    };

    stage(0, 0);
    int cur = 0;
    for (int t = 0; t < nsteps; ++t) {
        if (t + 1 < nsteps) {
            stage(cur ^ 1, t + 1);
            // wait only for STAGE(t)'s 2 loads; STAGE(t+1)'s 2 stay in flight
            asm volatile("s_waitcnt vmcnt(2)" ::: "memory");
        } else {
            asm volatile("s_waitcnt vmcnt(0)" ::: "memory");
        }
        asm volatile("s_barrier" ::: "memory");

        #pragma unroll
        for (int kk = 0; kk < 2; ++kk) {
            bf16x8 a[2], b[2];
            #pragma unroll
            for (int m = 0; m < 2; ++m) {
                const int row = wr * 32 + m * 16 + l15;
                const int chunk = (kk * 4 + l16) ^ (lane & 7);  // swizzled read
                a[m] = *(const bf16x8*)&As[cur][row * 64 + chunk * 8];
            }
            #pragma unroll
            for (int n = 0; n < 2; ++n) {
                const int row = wc * 32 + n * 16 + l15;
                const int chunk = (kk * 4 + l16) ^ (lane & 7);
                b[n] = *(const bf16x8*)&Bs[cur][row * 64 + chunk * 8];
            }
            #pragma unroll
            for (int m = 0; m < 2; ++m)
                #pragma unroll
                for (int n = 0; n < 2; ++n)
                    acc[m][n] = __builtin_amdgcn_mfma_f32_16x16x32_bf16(a[m], b[n], acc[m][n], 0, 0, 0);
        }
        asm volatile("s_barrier" ::: "memory");  // reads done before buf[cur] is re-staged
        cur ^= 1;
    }

    // ---- epilogue: bias (+GELU), masked/scattered store
    #pragma unroll
    for (int n = 0; n < 2; ++n) {
        const int col = n0 + wc * 32 + n * 16 + l15;
        const float bv = biasp[col];
        #pragma unroll
        for (int m = 0; m < 2; ++m) {
            #pragma unroll
            for (int r = 0; r < 4; ++r) {
                const int row_local = wr * 32 + m * 16 + l16 * 4 + r;
                if constexpr (EXPERT) {
                    if (mloc0 + row_local >= count) continue;
                }
                float v = acc[m][n][r] + bv;
                if constexpr (GELU_OUT) v = gelu_exact(v);
                int orow = m0 + row_local;
                if constexpr (SCATTER_OUT) orow = perm[orow];
                if constexpr (OUT_BF16)
                    ((bf16_t*)Cout)[(size_t)orow * N + col] = (bf16_t)v;
                else
                    ((float*)Cout)[(size_t)orow * N + col] = v;
            }
        }
    }
}

extern "C" void kernel_launch(void* const* d_in, const int* in_sizes, int n_in,
                              void* d_out, int out_size, void* d_ws, size_t ws_size,
                              hipStream_t stream) {
    const float* x     = (const float*)d_in[0];
    const int*   genre = (const int*)  d_in[1];
    const float* W1    = (const float*)d_in[2];
    const float* b1    = (const float*)d_in[3];
    const float* W2    = (const float*)d_in[4];
    const float* b2    = (const float*)d_in[5];
    const float* Wa    = (const float*)d_in[6];
    const float* ba    = (const float*)d_in[7];
    const float* Wb    = (const float*)d_in[8];
    const float* bb    = (const float*)d_in[9];
    float* out = (float*)d_out;

    char* ws = (char*)d_ws;
    const size_t MB = 1 << 20;
    bf16_t* W1t = (bf16_t*)(ws);                 // 1 MB  [1024][512]
    bf16_t* W2t = (bf16_t*)(ws + 1 * MB);        // 2 MB  [1024][1024]
    bf16_t* Wat = (bf16_t*)(ws + 3 * MB);        // 32 MB [16][1024][1024]
    bf16_t* Wbt = (bf16_t*)(ws + 35 * MB);       // 32 MB
    bf16_t* xb  = (bf16_t*)(ws + 67 * MB);       // 4 MB  [4096][512]
    bf16_t* s1b = (bf16_t*)(ws + 71 * MB);       // 8 MB  [4096][1024] (reused as h)
    bf16_t* sb  = (bf16_t*)(ws + 79 * MB);       // 8 MB
    int*    perm    = (int*)(ws + 87 * MB);      // 16 KB
    int*    offsets = (int*)(ws + 87 * MB + 65536);
    bf16_t* hb = s1b;  // s1 dead after GEMM2

    build_perm_kernel<<<1, 256, 0, stream>>>(genre, perm, offsets);
    convert_x_kernel<<<BATCH * INDIM / (256 * 8), 256, 0, stream>>>(x, xb);
    // W1: K=512 -> NT=2, 4-way ksplit? K/(64*NTsplit): use NT=2, y=4 -> 512 rows
    transpose_strip_kernel<INDIM / 256><<<dim3(NDIM / 64, 4, 1), 256, 0, stream>>>(
        W1, W1t, NDIM, INDIM);
    transpose_strip_kernel<NDIM / 256><<<dim3(NDIM / 64, 4, 1), 256, 0, stream>>>(
        W2, W2t, NDIM, NDIM);
    transpose_strip2_kernel<<<dim3(NDIM / 64, 4, 2 * NG), 256, 0, stream>>>(
        Wa, Wat, Wb, Wbt);

    // trunk: s1 = gelu(x @ W1 + b1)
    gemm128_kernel<false, false, true, false, true><<<dim3(32, 8), 1024, 0, stream>>>(
        xb, W1t, b1, s1b, INDIM, nullptr, nullptr);
    // trunk: s = gelu(s1 @ W2 + b2)
    gemm128_kernel<false, false, true, false, true><<<dim3(32, 8), 1024, 0, stream>>>(
        s1b, W2t, b2, sb, NDIM, nullptr, nullptr);
    // experts: h[perm-space] = gelu(s[perm] @ Wa[g] + ba[g])
    gemm128_kernel<true, true, true, false, true><<<dim3(48, 8), 1024, 0, stream>>>(
        sb, Wat, ba, hb, NDIM, perm, offsets);
    // experts: out[perm] = h @ Wb[g] + bb[g]
    gemm128_kernel<true, false, false, true, false><<<dim3(48, 8), 1024, 0, stream>>>(
        hb, Wbt, bb, out, NDIM, perm, offsets);
}

// Round 15
// 137.313 us; speedup vs baseline: 1.0904x; 1.0683x over previous
//
#include <hip/hip_runtime.h>
#include <hip/hip_bf16.h>
#include <math.h>

#define BATCH 4096
#define INDIM 512
#define NDIM  1024
#define NG    16

typedef __bf16 bf16_t;
typedef __bf16 bf16x8 __attribute__((ext_vector_type(8)));
typedef float  f32x4  __attribute__((ext_vector_type(4)));
typedef unsigned int u32;
typedef unsigned int u32x4 __attribute__((ext_vector_type(4)));

__device__ __forceinline__ float gelu_exact(float v) {
    return 0.5f * v * (1.0f + erff(v * 0.70710678118654752440f));
}

__device__ __forceinline__ void gload_lds16(const void* g, void* l) {
    __builtin_amdgcn_global_load_lds((const __attribute__((address_space(1))) void*)g,
                                     (__attribute__((address_space(3))) void*)l,
                                     16, 0, 0);
}

__device__ __forceinline__ u32 pkbf(float a, float b) {
    union { bf16_t h[2]; u32 v; } x;
    x.h[0] = (bf16_t)a; x.h[1] = (bf16_t)b;
    return x.v;
}

template<int N> __device__ __forceinline__ void waitvm() {
    if constexpr (N == 0)       asm volatile("s_waitcnt vmcnt(0)"  ::: "memory");
    else if constexpr (N == 2)  asm volatile("s_waitcnt vmcnt(2)"  ::: "memory");
    else if constexpr (N == 4)  asm volatile("s_waitcnt vmcnt(4)"  ::: "memory");
    else if constexpr (N == 8)  asm volatile("s_waitcnt vmcnt(8)"  ::: "memory");
    else                        asm volatile("s_waitcnt vmcnt(10)" ::: "memory");
}

// ---- transpose strip body, 256 threads, ONE strip per block (r12-validated) ----
// fp32 [K][N] -> bf16 [N][K]; 2-deep reg prefetch, counted vmcnt, LDS dbuf.
template<int NT>
__device__ __forceinline__ void strip_body(const float* __restrict__ src,
                                           bf16_t* __restrict__ dst,
                                           int N, int K, int n0, int kbase,
                                           int t, u32* __restrict__ Tsh) {
    const int kp_l = t >> 4;          // 0..15
    const int nc   = (t & 15) * 4;    // 0..60
    const int kr0  = kp_l * 2;
    const int n    = t >> 2;          // 0..63
    const int c4   = (t & 3) * 4;     // 0,4,8,12

    f32x4 r[3][4];

    auto load = [&](int slot, int kt) {
        const float* p = src + (size_t)(kbase + kt * 64 + kr0) * N + n0 + nc;
        r[slot][0] = *(const f32x4*)p;
        r[slot][1] = *(const f32x4*)(p + N);
        r[slot][2] = *(const f32x4*)(p + 32 * N);
        r[slot][3] = *(const f32x4*)(p + 33 * N);
        __builtin_amdgcn_sched_barrier(0);
    };
    auto pack = [&](int slot, int buf) {
        u32* Tb = Tsh + buf * (64 * 34);
        Tb[(nc + 0) * 34 + kp_l]      = pkbf(r[slot][0][0], r[slot][1][0]);
        Tb[(nc + 1) * 34 + kp_l]      = pkbf(r[slot][0][1], r[slot][1][1]);
        Tb[(nc + 2) * 34 + kp_l]      = pkbf(r[slot][0][2], r[slot][1][2]);
        Tb[(nc + 3) * 34 + kp_l]      = pkbf(r[slot][0][3], r[slot][1][3]);
        Tb[(nc + 0) * 34 + 16 + kp_l] = pkbf(r[slot][2][0], r[slot][3][0]);
        Tb[(nc + 1) * 34 + 16 + kp_l] = pkbf(r[slot][2][1], r[slot][3][1]);
        Tb[(nc + 2) * 34 + 16 + kp_l] = pkbf(r[slot][2][2], r[slot][3][2]);
        Tb[(nc + 3) * 34 + 16 + kp_l] = pkbf(r[slot][2][3], r[slot][3][3]);
    };
    auto flush = [&](int buf, int kt) {
        u32* Tb = Tsh + buf * (64 * 34);
        u32 v[8];
        #pragma unroll
        for (int j = 0; j < 4; ++j) v[j]     = Tb[n * 34 + c4 + j];
        #pragma unroll
        for (int j = 0; j < 4; ++j) v[4 + j] = Tb[n * 34 + 16 + c4 + j];
        u32* d = (u32*)((char*)dst + ((size_t)(n0 + n) * K + kbase + kt * 64) * 2);
        *(u32x4*)(d + c4)      = (u32x4){v[0], v[1], v[2], v[3]};
        *(u32x4*)(d + 16 + c4) = (u32x4){v[4], v[5], v[6], v[7]};
    };

    load(0, 0);
    if constexpr (NT > 1) load(1, 1);
    #pragma unroll
    for (int kt = 0; kt < NT; ++kt) {
        if (kt + 2 < NT) load((kt + 2) % 3, kt + 2);
        if (kt + 2 < NT) {
            if (kt == 0) waitvm<8>(); else waitvm<10>();
        } else if (kt + 1 < NT) {
            if (kt == 0) waitvm<4>(); else waitvm<8>();
        } else {
            if (kt == 0) waitvm<0>();
            else if (kt == 1) waitvm<2>();
            else waitvm<4>();
        }
        pack(kt % 3, kt & 1);
        asm volatile("s_waitcnt lgkmcnt(0)" ::: "memory");
        asm volatile("s_barrier" ::: "memory");
        flush(kt & 1, kt);
    }
}

// ---- prep mega-kernel: perm | convert_x | T(W1) | T(W2), role by blockIdx ----
// (bisect round: this is the kept half of the r13/r14 fusion; all bodies are
//  r12-passing, only the dispatch is merged. If the tripwire fires this round,
//  prep is the culprit; if not, the mixed GEMM+transpose fused_kernel was.)
#define PREP_CVT_BLOCKS 1024
#define PREP_W1_GROUPS  64
#define PREP_W2_GROUPS  64
__global__ __launch_bounds__(256)
void prep_kernel(const int* __restrict__ genre, int* __restrict__ perm,
                 int* __restrict__ offsets,
                 const float* __restrict__ x, bf16_t* __restrict__ xb,
                 const float* __restrict__ W1, bf16_t* __restrict__ W1t,
                 const float* __restrict__ W2, bf16_t* __restrict__ W2t) {
    __shared__ char smem[17408];
    const int bx = blockIdx.x;
    const int t  = threadIdx.x;

    if (bx == 0) {
        int (*cc)[NG] = (int(*)[NG])smem;
        int* gtot = (int*)(smem + 4096);
        int* goff = (int*)(smem + 4096 + 256);
        for (int i = t; i < 64 * NG; i += 256) (&cc[0][0])[i] = 0;
        __syncthreads();
        if (t < 64) {
            #pragma unroll 1
            for (int i = 0; i < 64; ++i) {
                int g = genre[t * 64 + i] & (NG - 1);
                cc[t][g] += 1;
            }
        }
        __syncthreads();
        if (t < NG) {
            int s = 0;
            #pragma unroll 1
            for (int c = 0; c < 64; ++c) { int v = cc[c][t]; cc[c][t] = s; s += v; }
            gtot[t] = s;
        }
        __syncthreads();
        if (t == 0) {
            int s = 0;
            for (int g = 0; g < NG; ++g) { goff[g] = s; offsets[g] = s; s += gtot[g]; }
            offsets[NG] = s;
        }
        __syncthreads();
        if (t < 64) {
            #pragma unroll 1
            for (int i = 0; i < 64; ++i) {
                int b = t * 64 + i;
                int g = genre[b] & (NG - 1);
                int pos = goff[g] + cc[t][g];
                cc[t][g] += 1;
                perm[pos] = b;
            }
        }
    } else if (bx < 1 + PREP_CVT_BLOCKS) {
        const int i = ((bx - 1) * 256 + t) * 8;
        float4 a = *(const float4*)&x[i];
        float4 b = *(const float4*)&x[i + 4];
        bf16x8 w;
        w[0] = (bf16_t)a.x; w[1] = (bf16_t)a.y; w[2] = (bf16_t)a.z; w[3] = (bf16_t)a.w;
        w[4] = (bf16_t)b.x; w[5] = (bf16_t)b.y; w[6] = (bf16_t)b.z; w[7] = (bf16_t)b.w;
        *(bf16x8*)&xb[i] = w;
    } else if (bx < 1 + PREP_CVT_BLOCKS + PREP_W1_GROUPS) {
        const int gid  = bx - 1 - PREP_CVT_BLOCKS;
        const int band = gid >> 2, ksl = gid & 3;
        strip_body<INDIM / 256>(W1, W1t, NDIM, INDIM, band * 64, ksl * (INDIM / 4),
                                t, (u32*)smem);
    } else {
        const int gid  = bx - 1 - PREP_CVT_BLOCKS - PREP_W1_GROUPS;
        const int band = gid >> 2, ksl = gid & 3;
        strip_body<NDIM / 256>(W2, W2t, NDIM, NDIM, band * 64, ksl * (NDIM / 4),
                               t, (u32*)smem);
    }
}

// ---- standalone Wa/Wb transpose (r12 form): z<16 -> Wa slab z, else Wb ----
__global__ __launch_bounds__(256)
void transpose_strip2_kernel(const float* __restrict__ srcA, bf16_t* __restrict__ dstA,
                             const float* __restrict__ srcB, bf16_t* __restrict__ dstB) {
    __shared__ u32 T[2 * 64 * 34];
    const int z = blockIdx.z;
    const size_t slab = (size_t)(z & 15) * NDIM * NDIM;
    const float* s = (z < 16 ? srcA : srcB) + slab;
    bf16_t*      d = (z < 16 ? dstA : dstB) + slab;
    strip_body<NDIM / 256>(s, d, NDIM, NDIM, blockIdx.x * 64,
                           blockIdx.y * (NDIM / 4), threadIdx.x, T);
}

// ---- 128x128 MFMA GEMM, 1024 threads (16 waves, 4x4), 2-phase + T2 XOR swizzle ----
// (exact round-12 structure: measured + tripwire-passing champion)
template<bool EXPERT, bool GATHER_A, bool GELU_OUT, bool SCATTER_OUT, bool OUT_BF16>
__global__ __launch_bounds__(1024, 4)
void gemm128_kernel(const bf16_t* __restrict__ A,
                    const bf16_t* __restrict__ Bt,
                    const float* __restrict__ bias,
                    void* __restrict__ Cout,
                    int K,
                    const int* __restrict__ perm,
                    const int* __restrict__ offsets) {
    constexpr int N = NDIM;
    __shared__ bf16_t As[2][128 * 64];
    __shared__ bf16_t Bs[2][128 * 64];

    const int n0 = blockIdx.y * 128;
    int m0 = 0, mloc0 = 0, count = 1 << 30, gbase = 0;
    const bf16_t* Bp = Bt;
    const float* biasp = bias;

    if constexpr (EXPERT) {
        const int bx = blockIdx.x;
        int g = 0, accum = 0, cnt = 0;
        for (; g < NG; ++g) {
            cnt = offsets[g + 1] - offsets[g];
            int nt = (cnt + 127) >> 7;
            if (bx < accum + nt) break;
            accum += nt;
        }
        if (g >= NG) return;
        count = cnt;
        mloc0 = (bx - accum) * 128;
        gbase = offsets[g];
        m0 = gbase + mloc0;
        Bp = Bt + (size_t)g * N * NDIM;
        biasp = bias + g * N;
    } else {
        m0 = blockIdx.x * 128;
    }

    const int tid  = threadIdx.x;
    const int wave = tid >> 6;
    const int lane = tid & 63;
    const int l15  = lane & 15;
    const int l16  = lane >> 4;
    const int wr   = wave >> 2;
    const int wc   = wave & 3;

    const int srow   = tid >> 3;
    const int srcoff = (((tid & 7) ^ ((tid >> 3) & 7)) * 16);
    int arow;
    if constexpr (EXPERT) {
        int rcl = mloc0 + srow;
        if (rcl >= count) rcl = count - 1;
        arow = GATHER_A ? perm[gbase + rcl] : (gbase + rcl);
    } else {
        arow = m0 + srow;
    }
    const char* aptr = (const char*)(A + (size_t)arow * K) + srcoff;
    const char* bptr = (const char*)(Bp + (size_t)(n0 + srow) * K) + srcoff;

    f32x4 acc[2][2];
    #pragma unroll
    for (int m = 0; m < 2; ++m)
        #pragma unroll
        for (int n = 0; n < 2; ++n)
            acc[m][n] = (f32x4){0.f, 0.f, 0.f, 0.f};

    const int nsteps = K >> 6;
    const int w1024 = wave * 1024;

    auto stage = [&](int buf, int t) {
        const size_t ko = (size_t)t * 128;
        gload_lds16(aptr + ko, (char*)&As[buf][0] + w1024);
        gload_lds16(bptr + ko, (char*)&Bs[buf][0] + w1024);
    };

    stage(0, 0);
    int cur = 0;
    for (int t = 0; t < nsteps; ++t) {
        if (t + 1 < nsteps) {
            stage(cur ^ 1, t + 1);
            asm volatile("s_waitcnt vmcnt(2)" ::: "memory");
        } else {
            asm volatile("s_waitcnt vmcnt(0)" ::: "memory");
        }
        asm volatile("s_barrier" ::: "memory");

        #pragma unroll
        for (int kk = 0; kk < 2; ++kk) {
            bf16x8 a[2], b[2];
            #pragma unroll
            for (int m = 0; m < 2; ++m) {
                const int row = wr * 32 + m * 16 + l15;
                const int chunk = (kk * 4 + l16) ^ (lane & 7);
                a[m] = *(const bf16x8*)&As[cur][row * 64 + chunk * 8];
            }
            #pragma unroll
            for (int n = 0; n < 2; ++n) {
                const int row = wc * 32 + n * 16 + l15;
                const int chunk = (kk * 4 + l16) ^ (lane & 7);
                b[n] = *(const bf16x8*)&Bs[cur][row * 64 + chunk * 8];
            }
            #pragma unroll
            for (int m = 0; m < 2; ++m)
                #pragma unroll
                for (int n = 0; n < 2; ++n)
                    acc[m][n] = __builtin_amdgcn_mfma_f32_16x16x32_bf16(a[m], b[n], acc[m][n], 0, 0, 0);
        }
        asm volatile("s_barrier" ::: "memory");
        cur ^= 1;
    }

    #pragma unroll
    for (int n = 0; n < 2; ++n) {
        const int col = n0 + wc * 32 + n * 16 + l15;
        const float bv = biasp[col];
        #pragma unroll
        for (int m = 0; m < 2; ++m) {
            #pragma unroll
            for (int r = 0; r < 4; ++r) {
                const int row_local = wr * 32 + m * 16 + l16 * 4 + r;
                if constexpr (EXPERT) {
                    if (mloc0 + row_local >= count) continue;
                }
                float v = acc[m][n][r] + bv;
                if constexpr (GELU_OUT) v = gelu_exact(v);
                int orow = m0 + row_local;
                if constexpr (SCATTER_OUT) orow = perm[orow];
                if constexpr (OUT_BF16)
                    ((bf16_t*)Cout)[(size_t)orow * N + col] = (bf16_t)v;
                else
                    ((float*)Cout)[(size_t)orow * N + col] = v;
            }
        }
    }
}

extern "C" void kernel_launch(void* const* d_in, const int* in_sizes, int n_in,
                              void* d_out, int out_size, void* d_ws, size_t ws_size,
                              hipStream_t stream) {
    const float* x     = (const float*)d_in[0];
    const int*   genre = (const int*)  d_in[1];
    const float* W1    = (const float*)d_in[2];
    const float* b1    = (const float*)d_in[3];
    const float* W2    = (const float*)d_in[4];
    const float* b2    = (const float*)d_in[5];
    const float* Wa    = (const float*)d_in[6];
    const float* ba    = (const float*)d_in[7];
    const float* Wb    = (const float*)d_in[8];
    const float* bb    = (const float*)d_in[9];
    float* out = (float*)d_out;

    char* ws = (char*)d_ws;
    const size_t MB = 1 << 20;
    bf16_t* W1t = (bf16_t*)(ws);                 // 1 MB  [1024][512]
    bf16_t* W2t = (bf16_t*)(ws + 1 * MB);        // 2 MB  [1024][1024]
    bf16_t* Wat = (bf16_t*)(ws + 3 * MB);        // 32 MB [16][1024][1024]
    bf16_t* Wbt = (bf16_t*)(ws + 35 * MB);       // 32 MB
    bf16_t* xb  = (bf16_t*)(ws + 67 * MB);       // 4 MB
    bf16_t* s1b = (bf16_t*)(ws + 71 * MB);       // 8 MB (reused as h)
    bf16_t* sb  = (bf16_t*)(ws + 79 * MB);       // 8 MB
    int*    perm    = (int*)(ws + 87 * MB);      // 16 KB
    int*    offsets = (int*)(ws + 87 * MB + 65536);
    bf16_t* hb = s1b;  // s1 dead after GEMM2

    // L0: perm | x->bf16 | T(W1) | T(W2) merged (bisect: kept half of fusion)
    prep_kernel<<<1 + PREP_CVT_BLOCKS + PREP_W1_GROUPS + PREP_W2_GROUPS, 256, 0, stream>>>(
        genre, perm, offsets, x, xb, W1, W1t, W2, W2t);
    // L1: Wa+Wb transpose (r12 standalone form)
    transpose_strip2_kernel<<<dim3(NDIM / 64, 4, 2 * NG), 256, 0, stream>>>(
        Wa, Wat, Wb, Wbt);
    // L2: trunk s1 = gelu(x @ W1 + b1)
    gemm128_kernel<false, false, true, false, true><<<dim3(32, 8), 1024, 0, stream>>>(
        xb, W1t, b1, s1b, INDIM, nullptr, nullptr);
    // L3: trunk s = gelu(s1 @ W2 + b2)
    gemm128_kernel<false, false, true, false, true><<<dim3(32, 8), 1024, 0, stream>>>(
        s1b, W2t, b2, sb, NDIM, nullptr, nullptr);
    // L4: experts h = gelu(s[perm] @ Wa[g] + ba[g])
    gemm128_kernel<true, true, true, false, true><<<dim3(48, 8), 1024, 0, stream>>>(
        sb, Wat, ba, hb, NDIM, perm, offsets);
    // L5: experts out[perm] = h @ Wb[g] + bb[g]
    gemm128_kernel<true, false, false, true, false><<<dim3(48, 8), 1024, 0, stream>>>(
        hb, Wbt, bb, out, NDIM, perm, offsets);
}

// Round 16
// 122.155 us; speedup vs baseline: 1.2257x; 1.1241x over previous
//
#include <hip/hip_runtime.h>
#include <hip/hip_bf16.h>
#include <math.h>

#define BATCH 4096
#define INDIM 512
#define NDIM  1024
#define NG    16

typedef __bf16 bf16_t;
typedef __bf16 bf16x8 __attribute__((ext_vector_type(8)));
typedef float  f32x4  __attribute__((ext_vector_type(4)));
typedef unsigned int u32;
typedef unsigned int u32x2 __attribute__((ext_vector_type(2)));
typedef unsigned int u32x4 __attribute__((ext_vector_type(4)));

__device__ __forceinline__ float gelu_exact(float v) {
    return 0.5f * v * (1.0f + erff(v * 0.70710678118654752440f));
}

__device__ __forceinline__ void gload_lds16(const void* g, void* l) {
    __builtin_amdgcn_global_load_lds((const __attribute__((address_space(1))) void*)g,
                                     (__attribute__((address_space(3))) void*)l,
                                     16, 0, 0);
}

__device__ __forceinline__ u32 pkbf(float a, float b) {
    union { bf16_t h[2]; u32 v; } x;
    x.h[0] = (bf16_t)a; x.h[1] = (bf16_t)b;
    return x.v;
}

template<int N> __device__ __forceinline__ void waitvm() {
    if constexpr (N == 0)       asm volatile("s_waitcnt vmcnt(0)"  ::: "memory");
    else if constexpr (N == 2)  asm volatile("s_waitcnt vmcnt(2)"  ::: "memory");
    else if constexpr (N == 4)  asm volatile("s_waitcnt vmcnt(4)"  ::: "memory");
    else if constexpr (N == 8)  asm volatile("s_waitcnt vmcnt(8)"  ::: "memory");
    else                        asm volatile("s_waitcnt vmcnt(10)" ::: "memory");
}

// ---- transpose strip body, 256 threads (r12/r15-validated, used in prep only) ----
template<int NT>
__device__ __forceinline__ void strip_body(const float* __restrict__ src,
                                           bf16_t* __restrict__ dst,
                                           int N, int K, int n0, int kbase,
                                           int t, u32* __restrict__ Tsh) {
    const int kp_l = t >> 4;
    const int nc   = (t & 15) * 4;
    const int kr0  = kp_l * 2;
    const int n    = t >> 2;
    const int c4   = (t & 3) * 4;

    f32x4 r[3][4];

    auto load = [&](int slot, int kt) {
        const float* p = src + (size_t)(kbase + kt * 64 + kr0) * N + n0 + nc;
        r[slot][0] = *(const f32x4*)p;
        r[slot][1] = *(const f32x4*)(p + N);
        r[slot][2] = *(const f32x4*)(p + 32 * N);
        r[slot][3] = *(const f32x4*)(p + 33 * N);
        __builtin_amdgcn_sched_barrier(0);
    };
    auto pack = [&](int slot, int buf) {
        u32* Tb = Tsh + buf * (64 * 34);
        Tb[(nc + 0) * 34 + kp_l]      = pkbf(r[slot][0][0], r[slot][1][0]);
        Tb[(nc + 1) * 34 + kp_l]      = pkbf(r[slot][0][1], r[slot][1][1]);
        Tb[(nc + 2) * 34 + kp_l]      = pkbf(r[slot][0][2], r[slot][1][2]);
        Tb[(nc + 3) * 34 + kp_l]      = pkbf(r[slot][0][3], r[slot][1][3]);
        Tb[(nc + 0) * 34 + 16 + kp_l] = pkbf(r[slot][2][0], r[slot][3][0]);
        Tb[(nc + 1) * 34 + 16 + kp_l] = pkbf(r[slot][2][1], r[slot][3][1]);
        Tb[(nc + 2) * 34 + 16 + kp_l] = pkbf(r[slot][2][2], r[slot][3][2]);
        Tb[(nc + 3) * 34 + 16 + kp_l] = pkbf(r[slot][2][3], r[slot][3][3]);
    };
    auto flush = [&](int buf, int kt) {
        u32* Tb = Tsh + buf * (64 * 34);
        u32 v[8];
        #pragma unroll
        for (int j = 0; j < 4; ++j) v[j]     = Tb[n * 34 + c4 + j];
        #pragma unroll
        for (int j = 0; j < 4; ++j) v[4 + j] = Tb[n * 34 + 16 + c4 + j];
        u32* d = (u32*)((char*)dst + ((size_t)(n0 + n) * K + kbase + kt * 64) * 2);
        *(u32x4*)(d + c4)      = (u32x4){v[0], v[1], v[2], v[3]};
        *(u32x4*)(d + 16 + c4) = (u32x4){v[4], v[5], v[6], v[7]};
    };

    load(0, 0);
    if constexpr (NT > 1) load(1, 1);
    #pragma unroll
    for (int kt = 0; kt < NT; ++kt) {
        if (kt + 2 < NT) load((kt + 2) % 3, kt + 2);
        if (kt + 2 < NT) {
            if (kt == 0) waitvm<8>(); else waitvm<10>();
        } else if (kt + 1 < NT) {
            if (kt == 0) waitvm<4>(); else waitvm<8>();
        } else {
            if (kt == 0) waitvm<0>();
            else if (kt == 1) waitvm<2>();
            else waitvm<4>();
        }
        pack(kt % 3, kt & 1);
        asm volatile("s_waitcnt lgkmcnt(0)" ::: "memory");
        asm volatile("s_barrier" ::: "memory");
        flush(kt & 1, kt);
    }
}

// ---- prep mega-kernel: perm | convert_x | T(W1) | T(W2)  (r15-passing) ----
#define PREP_CVT_BLOCKS 1024
#define PREP_W1_GROUPS  64
#define PREP_W2_GROUPS  64
__global__ __launch_bounds__(256)
void prep_kernel(const int* __restrict__ genre, int* __restrict__ perm,
                 int* __restrict__ offsets,
                 const float* __restrict__ x, bf16_t* __restrict__ xb,
                 const float* __restrict__ W1, bf16_t* __restrict__ W1t,
                 const float* __restrict__ W2, bf16_t* __restrict__ W2t) {
    __shared__ char smem[17408];
    const int bx = blockIdx.x;
    const int t  = threadIdx.x;

    if (bx == 0) {
        int (*cc)[NG] = (int(*)[NG])smem;
        int* gtot = (int*)(smem + 4096);
        int* goff = (int*)(smem + 4096 + 256);
        for (int i = t; i < 64 * NG; i += 256) (&cc[0][0])[i] = 0;
        __syncthreads();
        if (t < 64) {
            #pragma unroll 1
            for (int i = 0; i < 64; ++i) {
                int g = genre[t * 64 + i] & (NG - 1);
                cc[t][g] += 1;
            }
        }
        __syncthreads();
        if (t < NG) {
            int s = 0;
            #pragma unroll 1
            for (int c = 0; c < 64; ++c) { int v = cc[c][t]; cc[c][t] = s; s += v; }
            gtot[t] = s;
        }
        __syncthreads();
        if (t == 0) {
            int s = 0;
            for (int g = 0; g < NG; ++g) { goff[g] = s; offsets[g] = s; s += gtot[g]; }
            offsets[NG] = s;
        }
        __syncthreads();
        if (t < 64) {
            #pragma unroll 1
            for (int i = 0; i < 64; ++i) {
                int b = t * 64 + i;
                int g = genre[b] & (NG - 1);
                int pos = goff[g] + cc[t][g];
                cc[t][g] += 1;
                perm[pos] = b;
            }
        }
    } else if (bx < 1 + PREP_CVT_BLOCKS) {
        const int i = ((bx - 1) * 256 + t) * 8;
        float4 a = *(const float4*)&x[i];
        float4 b = *(const float4*)&x[i + 4];
        bf16x8 w;
        w[0] = (bf16_t)a.x; w[1] = (bf16_t)a.y; w[2] = (bf16_t)a.z; w[3] = (bf16_t)a.w;
        w[4] = (bf16_t)b.x; w[5] = (bf16_t)b.y; w[6] = (bf16_t)b.z; w[7] = (bf16_t)b.w;
        *(bf16x8*)&xb[i] = w;
    } else if (bx < 1 + PREP_CVT_BLOCKS + PREP_W1_GROUPS) {
        const int gid  = bx - 1 - PREP_CVT_BLOCKS;
        const int band = gid >> 2, ksl = gid & 3;
        strip_body<INDIM / 256>(W1, W1t, NDIM, INDIM, band * 64, ksl * (INDIM / 4),
                                t, (u32*)smem);
    } else {
        const int gid  = bx - 1 - PREP_CVT_BLOCKS - PREP_W1_GROUPS;
        const int band = gid >> 2, ksl = gid & 3;
        strip_body<NDIM / 256>(W2, W2t, NDIM, NDIM, band * 64, ksl * (NDIM / 4),
                               t, (u32*)smem);
    }
}

// ---- race-proof transpose role: 1024 threads, plain __syncthreads only ----
// fp32 [1024][1024] slab -> bf16 [N][K]; one block owns a 64-col band, loops
// 16 k-tiles. No hand-rolled waitcnt: __syncthreads drains vmcnt/lgkm (compiler
// -emitted), so no issue-order bookkeeping to be broken by scheduling (the
// r13/r14 race class). 1-deep reg prefetch; LDS fp32 [2][64][71] (pad 71).
__device__ __forceinline__ void tr1024_body(const float* __restrict__ src,
                                            bf16_t* __restrict__ dst,
                                            int n0, char* smem) {
    float* T = (float*)smem;                 // [2][64][71] = 36352 B
    const int t   = threadIdx.x;
    const int row = t >> 4;                  // 0..63 (k-row within tile)
    const int nc  = (t & 15) * 4;            // 0..60 (col within band)
    const int n   = t >> 4;                  // 0..63 (flush: n-row)
    const int kq  = t & 15;                  // 0..15 (flush: k-quad)

    f32x4 reg = *(const f32x4*)(src + (size_t)row * NDIM + n0 + nc);  // tile 0
    #pragma unroll 1
    for (int kt = 0; kt < 16; ++kt) {
        float* Tb = T + (kt & 1) * (64 * 71);
        *(f32x4*)&Tb[row * 71 + nc] = reg;
        if (kt + 1 < 16)
            reg = *(const f32x4*)(src + (size_t)((kt + 1) * 64 + row) * NDIM + n0 + nc);
        __syncthreads();
        const float f0 = Tb[(kq * 4 + 0) * 71 + n];
        const float f1 = Tb[(kq * 4 + 1) * 71 + n];
        const float f2 = Tb[(kq * 4 + 2) * 71 + n];
        const float f3 = Tb[(kq * 4 + 3) * 71 + n];
        u32x2 v;
        v.x = pkbf(f0, f1);
        v.y = pkbf(f2, f3);
        // dst row n0+n, k offset kt*64 + kq*4 (bf16): 16 thr x 8B = dense 128B/row
        *(u32x2*)((u32*)((char*)dst + ((size_t)(n0 + n) * NDIM + kt * 64) * 2) + kq * 2) = v;
        __syncthreads();   // flush reads done before next tile overwrites Tb
    }
}

// ---- trunk GEMM body: exact gemm128 1024-thr structure (6-round-proven) ----
__device__ __forceinline__ void trunk1024_body(const bf16_t* __restrict__ A,
                                               const bf16_t* __restrict__ Bt,
                                               const float* __restrict__ bias,
                                               bf16_t* __restrict__ Cout,
                                               int K, int m0, int n0, char* smem) {
    constexpr int N = NDIM;
    char* As = smem;            // [2][128*64] bf16 = 32 KB
    char* Bs = smem + 32768;    // [2][128*64] bf16 = 32 KB

    const int tid  = threadIdx.x;
    const int wave = tid >> 6;
    const int lane = tid & 63;
    const int l15  = lane & 15;
    const int l16  = lane >> 4;
    const int wr   = wave >> 2;
    const int wc   = wave & 3;

    const int srow   = tid >> 3;
    const int srcoff = (((tid & 7) ^ ((tid >> 3) & 7)) * 16);
    const char* aptr = (const char*)(A + (size_t)(m0 + srow) * K) + srcoff;
    const char* bptr = (const char*)(Bt + (size_t)(n0 + srow) * K) + srcoff;

    f32x4 acc[2][2];
    #pragma unroll
    for (int m = 0; m < 2; ++m)
        #pragma unroll
        for (int n = 0; n < 2; ++n)
            acc[m][n] = (f32x4){0.f, 0.f, 0.f, 0.f};

    const int nsteps = K >> 6;
    const int w1024 = wave * 1024;

    auto stage = [&](int buf, int t) {
        const size_t ko = (size_t)t * 128;
        gload_lds16(aptr + ko, As + buf * 16384 + w1024);
        gload_lds16(bptr + ko, Bs + buf * 16384 + w1024);
    };

    stage(0, 0);
    int cur = 0;
    for (int t = 0; t < nsteps; ++t) {
        if (t + 1 < nsteps) {
            stage(cur ^ 1, t + 1);
            asm volatile("s_waitcnt vmcnt(2)" ::: "memory");
        } else {
            asm volatile("s_waitcnt vmcnt(0)" ::: "memory");
        }
        asm volatile("s_barrier" ::: "memory");

        #pragma unroll
        for (int kk = 0; kk < 2; ++kk) {
            bf16x8 a[2], b[2];
            #pragma unroll
            for (int m = 0; m < 2; ++m) {
                const int row = wr * 32 + m * 16 + l15;
                const int chunk = (kk * 4 + l16) ^ (lane & 7);
                a[m] = *(const bf16x8*)(As + cur * 16384 + (row * 64 + chunk * 8) * 2);
            }
            #pragma unroll
            for (int n = 0; n < 2; ++n) {
                const int row = wc * 32 + n * 16 + l15;
                const int chunk = (kk * 4 + l16) ^ (lane & 7);
                b[n] = *(const bf16x8*)(Bs + cur * 16384 + (row * 64 + chunk * 8) * 2);
            }
            #pragma unroll
            for (int m = 0; m < 2; ++m)
                #pragma unroll
                for (int n = 0; n < 2; ++n)
                    acc[m][n] = __builtin_amdgcn_mfma_f32_16x16x32_bf16(a[m], b[n], acc[m][n], 0, 0, 0);
        }
        asm volatile("s_barrier" ::: "memory");
        cur ^= 1;
    }

    #pragma unroll
    for (int n = 0; n < 2; ++n) {
        const int col = n0 + wc * 32 + n * 16 + l15;
        const float bv = bias[col];
        #pragma unroll
        for (int m = 0; m < 2; ++m) {
            #pragma unroll
            for (int r = 0; r < 4; ++r) {
                const int row_local = wr * 32 + m * 16 + l16 * 4 + r;
                float v = gelu_exact(acc[m][n][r] + bv);
                Cout[(size_t)(m0 + row_local) * N + col] = (bf16_t)v;
            }
        }
    }
}

// ---- fused: trunk GEMM (even bx) + one weight-tensor transpose (odd bx) ----
// 512 blocks x 1024 thr. Chip-wide overlap: GEMM blocks are latency-bound with
// idle HBM; transpose blocks are the measured 2.3 TB/s long pole.
__global__ __launch_bounds__(1024, 2)
void fused_kernel(const bf16_t* __restrict__ A, const bf16_t* __restrict__ Bt,
                  const float* __restrict__ bias, bf16_t* __restrict__ Cout, int K,
                  const float* __restrict__ Wsrc, bf16_t* __restrict__ Wdst) {
    __shared__ char smem[65536];
    const int bx = blockIdx.x;
    if (bx & 1) {
        const int sid  = bx >> 1;        // 0..255
        const int slab = sid >> 4;       // 0..15
        const int band = sid & 15;       // 0..15
        tr1024_body(Wsrc + (size_t)slab * NDIM * NDIM,
                    Wdst + (size_t)slab * NDIM * NDIM, band * 64, smem);
    } else {
        const int gid = bx >> 1;         // 0..255
        trunk1024_body(A, Bt, bias, Cout, K, (gid & 31) * 128, (gid >> 5) * 128, smem);
    }
}

// ---- expert GEMM: r12/r15 champion, unchanged ----
template<bool GATHER_A, bool GELU_OUT, bool SCATTER_OUT, bool OUT_BF16>
__global__ __launch_bounds__(1024, 4)
void gemm128_kernel(const bf16_t* __restrict__ A,
                    const bf16_t* __restrict__ Bt,
                    const float* __restrict__ bias,
                    void* __restrict__ Cout,
                    int K,
                    const int* __restrict__ perm,
                    const int* __restrict__ offsets) {
    constexpr int N = NDIM;
    __shared__ bf16_t As[2][128 * 64];
    __shared__ bf16_t Bs[2][128 * 64];

    const int n0 = blockIdx.y * 128;
    int m0 = 0, mloc0 = 0, count = 1 << 30, gbase = 0;
    const bf16_t* Bp = Bt;
    const float* biasp = bias;

    {
        const int bx = blockIdx.x;
        int g = 0, accum = 0, cnt = 0;
        for (; g < NG; ++g) {
            cnt = offsets[g + 1] - offsets[g];
            int nt = (cnt + 127) >> 7;
            if (bx < accum + nt) break;
            accum += nt;
        }
        if (g >= NG) return;
        count = cnt;
        mloc0 = (bx - accum) * 128;
        gbase = offsets[g];
        m0 = gbase + mloc0;
        Bp = Bt + (size_t)g * N * NDIM;
        biasp = bias + g * N;
    }

    const int tid  = threadIdx.x;
    const int wave = tid >> 6;
    const int lane = tid & 63;
    const int l15  = lane & 15;
    const int l16  = lane >> 4;
    const int wr   = wave >> 2;
    const int wc   = wave & 3;

    const int srow   = tid >> 3;
    const int srcoff = (((tid & 7) ^ ((tid >> 3) & 7)) * 16);
    int arow;
    {
        int rcl = mloc0 + srow;
        if (rcl >= count) rcl = count - 1;
        arow = GATHER_A ? perm[gbase + rcl] : (gbase + rcl);
    }
    const char* aptr = (const char*)(A + (size_t)arow * K) + srcoff;
    const char* bptr = (const char*)(Bp + (size_t)(n0 + srow) * K) + srcoff;

    f32x4 acc[2][2];
    #pragma unroll
    for (int m = 0; m < 2; ++m)
        #pragma unroll
        for (int n = 0; n < 2; ++n)
            acc[m][n] = (f32x4){0.f, 0.f, 0.f, 0.f};

    const int nsteps = K >> 6;
    const int w1024 = wave * 1024;

    auto stage = [&](int buf, int t) {
        const size_t ko = (size_t)t * 128;
        gload_lds16(aptr + ko, (char*)&As[buf][0] + w1024);
        gload_lds16(bptr + ko, (char*)&Bs[buf][0] + w1024);
    };

    stage(0, 0);
    int cur = 0;
    for (int t = 0; t < nsteps; ++t) {
        if (t + 1 < nsteps) {
            stage(cur ^ 1, t + 1);
            asm volatile("s_waitcnt vmcnt(2)" ::: "memory");
        } else {
            asm volatile("s_waitcnt vmcnt(0)" ::: "memory");
        }
        asm volatile("s_barrier" ::: "memory");

        #pragma unroll
        for (int kk = 0; kk < 2; ++kk) {
            bf16x8 a[2], b[2];
            #pragma unroll
            for (int m = 0; m < 2; ++m) {
                const int row = wr * 32 + m * 16 + l15;
                const int chunk = (kk * 4 + l16) ^ (lane & 7);
                a[m] = *(const bf16x8*)&As[cur][row * 64 + chunk * 8];
            }
            #pragma unroll
            for (int n = 0; n < 2; ++n) {
                const int row = wc * 32 + n * 16 + l15;
                const int chunk = (kk * 4 + l16) ^ (lane & 7);
                b[n] = *(const bf16x8*)&Bs[cur][row * 64 + chunk * 8];
            }
            #pragma unroll
            for (int m = 0; m < 2; ++m)
                #pragma unroll
                for (int n = 0; n < 2; ++n)
                    acc[m][n] = __builtin_amdgcn_mfma_f32_16x16x32_bf16(a[m], b[n], acc[m][n], 0, 0, 0);
        }
        asm volatile("s_barrier" ::: "memory");
        cur ^= 1;
    }

    #pragma unroll
    for (int n = 0; n < 2; ++n) {
        const int col = n0 + wc * 32 + n * 16 + l15;
        const float bv = biasp[col];
        #pragma unroll
        for (int m = 0; m < 2; ++m) {
            #pragma unroll
            for (int r = 0; r < 4; ++r) {
                const int row_local = wr * 32 + m * 16 + l16 * 4 + r;
                if (mloc0 + row_local >= count) continue;
                float v = acc[m][n][r] + bv;
                if constexpr (GELU_OUT) v = gelu_exact(v);
                int orow = m0 + row_local;
                if constexpr (SCATTER_OUT) orow = perm[orow];
                if constexpr (OUT_BF16)
                    ((bf16_t*)Cout)[(size_t)orow * N + col] = (bf16_t)v;
                else
                    ((float*)Cout)[(size_t)orow * N + col] = v;
            }
        }
    }
}

extern "C" void kernel_launch(void* const* d_in, const int* in_sizes, int n_in,
                              void* d_out, int out_size, void* d_ws, size_t ws_size,
                              hipStream_t stream) {
    const float* x     = (const float*)d_in[0];
    const int*   genre = (const int*)  d_in[1];
    const float* W1    = (const float*)d_in[2];
    const float* b1    = (const float*)d_in[3];
    const float* W2    = (const float*)d_in[4];
    const float* b2    = (const float*)d_in[5];
    const float* Wa    = (const float*)d_in[6];
    const float* ba    = (const float*)d_in[7];
    const float* Wb    = (const float*)d_in[8];
    const float* bb    = (const float*)d_in[9];
    float* out = (float*)d_out;

    char* ws = (char*)d_ws;
    const size_t MB = 1 << 20;
    bf16_t* W1t = (bf16_t*)(ws);                 // 1 MB  [1024][512]
    bf16_t* W2t = (bf16_t*)(ws + 1 * MB);        // 2 MB  [1024][1024]
    bf16_t* Wat = (bf16_t*)(ws + 3 * MB);        // 32 MB [16][1024][1024]
    bf16_t* Wbt = (bf16_t*)(ws + 35 * MB);       // 32 MB
    bf16_t* xb  = (bf16_t*)(ws + 67 * MB);       // 4 MB
    bf16_t* s1b = (bf16_t*)(ws + 71 * MB);       // 8 MB (reused as h)
    bf16_t* sb  = (bf16_t*)(ws + 79 * MB);       // 8 MB
    int*    perm    = (int*)(ws + 87 * MB);      // 16 KB
    int*    offsets = (int*)(ws + 87 * MB + 65536);
    bf16_t* hb = s1b;  // s1 dead after L2

    // L0: perm | x->bf16 | T(W1) | T(W2)
    prep_kernel<<<1 + PREP_CVT_BLOCKS + PREP_W1_GROUPS + PREP_W2_GROUPS, 256, 0, stream>>>(
        genre, perm, offsets, x, xb, W1, W1t, W2, W2t);
    // L1: GEMM1 (s1 = gelu(x@W1+b1)) overlapped chip-wide with T(Wa)
    fused_kernel<<<512, 1024, 0, stream>>>(xb, W1t, b1, s1b, INDIM, Wa, Wat);
    // L2: GEMM2 (s = gelu(s1@W2+b2)) overlapped chip-wide with T(Wb)
    fused_kernel<<<512, 1024, 0, stream>>>(s1b, W2t, b2, sb, NDIM, Wb, Wbt);
    // L3: experts h = gelu(s[perm]@Wa[g]+ba[g])
    gemm128_kernel<true, true, false, true><<<dim3(48, 8), 1024, 0, stream>>>(
        sb, Wat, ba, hb, NDIM, perm, offsets);
    // L4: experts out[perm] = h@Wb[g]+bb[g]
    gemm128_kernel<false, false, true, false><<<dim3(48, 8), 1024, 0, stream>>>(
        hb, Wbt, bb, out, NDIM, perm, offsets);
}